// Round 4
// baseline (101.644 us; speedup 1.0000x reference)
//
#include <hip/hip_runtime.h>

#define ALPHA 0.25f
#define EPS   1e-8f
// COST_CLASS=2, COST_BBOX=5, COST_GIOU=2

// Problem constants (from setup_inputs): bs=16, Q=900, C=80, g_size=3
constexpr int BS = 16;
constexpr int QN = 900;
constexpr int CN = 80;
constexpr int GS = 3;
constexpr int QG_PER_BLOCK = 4;              // 4 query-groups per block
constexpr int ROWS = QG_PER_BLOCK * GS;      // 12 pred rows
constexpr int NT_THREADS = 320;              // 5 waves; 1600 % 320 == 0 -> 5 exact iters

typedef float v2f __attribute__((ext_vector_type(2)));

static __device__ __forceinline__ v2f vabs2(v2f a) {
    return (v2f){ fabsf(a.x), fabsf(a.y) };
}
static __device__ __forceinline__ v2f vmax2(v2f a, v2f b) {
    return (v2f){ fmaxf(a.x, b.x), fmaxf(a.y, b.y) };
}

// ---------------------------------------------------------------------------
// v3 (resubmit, unchanged): exact-division t-loop + packed-f32 geometry.
//  - block = 320 threads, grid = (75 qg-tiles, 16 batches); each thread does
//    exactly T/320 = 5 t-iterations -> no bounds checks, no tail.
//  - x/y-symmetric box math in float2 ext-vectors -> v_pk_{add,sub,max}_f32;
//    dx1 = dx0 + (w - tw) eliminates the x1/y1 register arrays (-24 VGPR).
//  - depth-1 prefetch of next target box+label kept (trip count 5).
//  - nontemporal stores: the 30.7 MB output stream stops evicting the
//    L2-resident targets/logits.
// ---------------------------------------------------------------------------
template<int NITER>   // >0: exact compile-time trip count; 0: generic runtime
__global__ __launch_bounds__(NT_THREADS, 4) void fused_cost_kernel(
    const float* __restrict__ pred_logits,  // [BS*QN, CN]
    const float* __restrict__ pred_boxes,   // [BS*QN, 4] cxcywh
    const int*   __restrict__ tgt_labels,   // [T]
    const float* __restrict__ tgt_boxes,    // [T, 4] cxcywh
    float*       __restrict__ out,          // [BS, QN/GS, T]
    int T)
{
    __shared__ __align__(16) float s_cc_t[CN * ROWS];  // [80][12] = 3840 B

    const int tid = threadIdx.x;
    const int qg0 = blockIdx.x * QG_PER_BLOCK;
    const int b   = blockIdx.y;
    const int n0  = b * QN + qg0 * GS;      // first of 12 pred rows

    // ---- focal class-cost rows from logits, transposed into LDS ----
    const float* lg0 = pred_logits + (size_t)n0 * CN;
    if (tid < (ROWS * CN) / 4) {            // 240 float4 loads
        const float4 x4 = ((const float4*)lg0)[tid];
        const int base = tid * 4;
        const int r = base / CN;
        const int c = base - r * CN;        // CN%4==0 -> all 4 share row r
        const float xs[4] = { x4.x, x4.y, x4.z, x4.w };
        #pragma unroll
        for (int i = 0; i < 4; ++i) {
            float p = __fdividef(1.0f, 1.0f + __expf(-xs[i]));  // sigmoid
            float omp = 1.0f - p;
            float pos = ALPHA * omp * omp * (-__logf(p + EPS));
            float neg = (1.0f - ALPHA) * p * p * (-__logf(omp + EPS));
            s_cc_t[(c + i) * ROWS + r] = pos - neg;
        }
    }

    // ---- pred rows -> registers: corner0, (w,h), area ----
    v2f P0[ROWS], PWH[ROWS];
    float Pa[ROWS];
    #pragma unroll
    for (int r = 0; r < ROWS; ++r) {
        const float4 pb = ((const float4*)pred_boxes)[n0 + r];
        PWH[r] = (v2f){ pb.z, pb.w };
        P0[r]  = (v2f){ pb.x - 0.5f * pb.z, pb.y - 0.5f * pb.w };
        Pa[r]  = pb.z * pb.w;
    }
    __syncthreads();

    const int qgTotal = QN / GS;                         // 300
    float* const o0 = out + (size_t)(b * qgTotal + qg0) * T;
    const v2f Z2 = { 0.0f, 0.0f };

    const int nIter = (NITER > 0) ? NITER : ((T + NT_THREADS - 1) / NT_THREADS);

    int t = tid;
    int tl = (NITER > 0) ? t : ((t < T) ? t : (T - 1));  // clamped load idx
    float4 tr  = ((const float4*)tgt_boxes)[tl];
    int    lab = tgt_labels[tl];

    for (int it = 0; it < nIter; ++it) {
        // ---- prefetch next iteration's target (clamped; hides L2 latency) ----
        const int tn = t + NT_THREADS;
        const int tc = (tn < T) ? tn : tl;
        const float4 trn  = ((const float4*)tgt_boxes)[tc];
        const int    labn = tgt_labels[tc];

        // ---- gather the 12 class costs for this label: 3x ds_read_b128 ----
        const float4* ccp = (const float4*)&s_cc_t[lab * ROWS];
        const float4 c0 = ccp[0], c1 = ccp[1], c2 = ccp[2];
        const float ccv[ROWS] = { c0.x, c0.y, c0.z, c0.w,
                                  c1.x, c1.y, c1.z, c1.w,
                                  c2.x, c2.y, c2.z, c2.w };

        const v2f T0  = (v2f){ tr.x - 0.5f * tr.z, tr.y - 0.5f * tr.w };
        const v2f TWH = (v2f){ tr.z, tr.w };
        const float ta = tr.z * tr.w;

        const bool doWrite = (NITER > 0) || (t < T);

        #pragma unroll
        for (int j = 0; j < QG_PER_BLOCK; ++j) {
            float m = -3.402823466e+38f;
            #pragma unroll
            for (int g = 0; g < GS; ++g) {
                const int i = j * GS + g;

                // packed corner/size deltas (x,y symmetric -> v_pk_*)
                const v2f D0 = P0[i] - T0;               // (dx0, dy0)
                const v2f WD = PWH[i] - TWH;             // (w-tw, h-th)
                const v2f D1 = D0 + WD;                  // (dx1, dy1)
                const v2f AB = vabs2(D0) + vabs2(D1);    // (abx, aby)
                const v2f S  = PWH[i] + TWH;             // (sx, sy)
                const v2f IWH = vmax2(S - AB, Z2);       // (2iw, 2ih)
                const v2f E  = S + AB;                   // (2ew, 2eh)
                const v2f DS = D0 + D1;

                const float inter4 = IWH.x * IWH.y;      // 4*inter
                const float earea4 = E.x * E.y;          // 4*earea
                // L1: |cx-tcx| = 0.5|dx0+dx1|; |w-tw| direct
                const float l1 = fmaf(0.5f, fabsf(DS.x) + fabsf(DS.y),
                                            fabsf(WD.x) + fabsf(WD.y));
                const float uni = fmaf(-0.25f, inter4, Pa[i] + ta);
                // g2 = 2*(inter*earea + uni^2)/(uni*earea)
                const float num = fmaf(0.5f * inter4, earea4, 8.0f * uni * uni);
                const float den = uni * earea4;
                const float g2  = __fdividef(num, den);

                // cost = 5*l1 + 2*cc - 2*giou = 5*l1 + 2*cc + 2 - g2
                const float cost = fmaf(5.0f, l1, fmaf(2.0f, ccv[i], 2.0f - g2));
                m = fmaxf(m, cost);
            }
            if (doWrite)
                __builtin_nontemporal_store(m, o0 + (size_t)j * T + t);
        }

        t = tn; tl = tc; tr = trn; lab = labn;
    }
}

extern "C" void kernel_launch(void* const* d_in, const int* in_sizes, int n_in,
                              void* d_out, int out_size, void* d_ws, size_t ws_size,
                              hipStream_t stream) {
    const float* pred_logits = (const float*)d_in[0];   // [16,900,80]
    const float* pred_boxes  = (const float*)d_in[1];   // [16,900,4]
    const int*   tgt_labels  = (const int*)d_in[2];     // [T]
    const float* tgt_boxes   = (const float*)d_in[3];   // [T,4]
    // d_in[4] = g_size (=3, hard-coded as GS)

    const int T = in_sizes[2];
    float* out = (float*)d_out;

    dim3 grid((QN / GS) / QG_PER_BLOCK, BS);            // 75 x 16 = 1200
    if (T == NT_THREADS * 5) {
        fused_cost_kernel<5><<<grid, NT_THREADS, 0, stream>>>(
            pred_logits, pred_boxes, tgt_labels, tgt_boxes, out, T);
    } else {
        fused_cost_kernel<0><<<grid, NT_THREADS, 0, stream>>>(
            pred_logits, pred_boxes, tgt_labels, tgt_boxes, out, T);
    }
}